// Round 17
// baseline (452.240 us; speedup 1.0000x reference)
//
#include <hip/hip_runtime.h>
#include <hip/hip_bf16.h>
#include <math.h>

#define NHEADS 10

typedef unsigned short ushort_t;
typedef unsigned int uint_t;

typedef __attribute__((ext_vector_type(4))) float f32x4;
typedef __attribute__((ext_vector_type(8))) short short8;

__device__ __forceinline__ float bu2f(ushort_t u){ return __uint_as_float(((uint_t)u)<<16); }
__device__ __forceinline__ ushort_t f2bu(float f){
    uint_t b = __float_as_uint(f);
    return (ushort_t)((b + 0x7FFFu + ((b>>16)&1u)) >> 16);   // RNE
}

// ---------------- CSR scan ----------------
__global__ void k_scan(int* cnt, int N, int ET, int* indptr){
    __shared__ int lds[1024];
    int t = threadIdx.x;
    int chunk = (N + 1023)/1024;
    int base = t*chunk;
    int s = 0;
    for(int i=0;i<chunk;i++){ int idx=base+i; if(idx<N) s += cnt[idx]; }
    lds[t]=s;
    __syncthreads();
    for(int off=1; off<1024; off<<=1){
        int v = (t>=off)? lds[t-off] : 0;
        __syncthreads();
        lds[t]+=v;
        __syncthreads();
    }
    int run = lds[t]-s;
    for(int i=0;i<chunk;i++){
        int idx=base+i;
        if(idx<N){
            int c = cnt[idx];
            indptr[idx]=run;
            cnt[idx]=run;
            run += c;
        }
    }
    if(t==0) indptr[N]=ET;
}

__global__ void k_fill(const int* eidx, int E, int N, int* cursor, int* srcs){
    int e = blockIdx.x*blockDim.x + threadIdx.x;
    int ET = E + N;
    if(e >= ET) return;
    int s, d;
    if(e < E){ s = eidx[e]; d = eidx[E+e]; } else { s = e-E; d = e-E; }
    int pos = atomicAdd(&cursor[d], 1);
    srcs[pos] = s;
}

// wave-parallel bitonic sort of each node's src segment (1 wave / node)
__global__ void k_sortw(const int* indptr, int* srcs, int N){
    int wid  = (blockIdx.x*blockDim.x + threadIdx.x) >> 6;
    int lane = threadIdx.x & 63;
    if(wid >= N) return;
    int p0 = indptr[wid], p1 = indptr[wid+1];
    int deg = p1 - p0;
    if(deg <= 1) return;
    if(deg <= 64){
        int v = (lane < deg) ? srcs[p0+lane] : 0x7FFFFFFF;
        #pragma unroll
        for(int k=2; k<=64; k<<=1){
            #pragma unroll
            for(int j=k>>1; j>0; j>>=1){
                int partner = __shfl_xor(v, j, 64);
                bool dir   = ((lane & k) == 0);
                bool small = ((lane & j) == 0);
                int mn = min(v, partner), mx = max(v, partner);
                v = (dir == small) ? mn : mx;
            }
        }
        if(lane < deg) srcs[p0+lane] = v;
    } else if(lane == 0){               // safety fallback, statistically never
        for(int i=p0+1;i<p1;i++){
            int v2 = srcs[i]; int j=i-1;
            while(j>=p0 && srcs[j]>v2){ srcs[j+1]=srcs[j]; j--; }
            srcs[j+1]=v2;
        }
    }
}

// ---------------- setup: weight transposes + fc0 + CSR count, one dispatch ----------------
__global__ void k_setup(const float* __restrict__ W1c,const float* __restrict__ W2c,
                        const float* __restrict__ W3c,const float* __restrict__ W4c,
                        ushort_t* T1,ushort_t* T2,ushort_t* T3,ushort_t* T4,
                        const float* __restrict__ x, const float* __restrict__ W0,
                        const float* __restrict__ b0, float* __restrict__ fc0o,
                        const int* __restrict__ eidx, int* cnt, int E, int N){
    int idx = blockIdx.x*blockDim.x + threadIdx.x;
    if(idx < 10240){ int c=idx/32, k=idx%32; T1[idx] = (k<16)? f2bu(W1c[(size_t)k*320+c]) : (ushort_t)0; return; }
    idx -= 10240;
    if(idx < 20480){ int c=idx/32, k=idx%32; T2[idx] = f2bu(W2c[(size_t)k*640+c]); return; }
    idx -= 20480;
    if(idx < 81920){ int c=idx/64, k=idx%64; T3[idx] = f2bu(W3c[(size_t)k*1280+c]); return; }
    idx -= 81920;
    if(idx < 32768){ int c=idx/128, k=idx%128; T4[idx] = f2bu(W4c[(size_t)k*256+c]); return; }
    idx -= 32768;
    if(idx < N*16){
        int n = idx>>4, c = idx&15;
        float acc = b0[c];
        #pragma unroll
        for(int k=0;k<24;k++) acc += x[n*24+k] * W0[k*16+c];
        fc0o[idx] = acc>0.f ? acc : expm1f(acc);
        return;
    }
    idx -= N*16;
    if(idx < E+N){
        int d = (idx < E) ? eidx[E + idx] : (idx - E);
        atomicAdd(&cnt[d], 1);
    }
}

// ---------------- LDS-free MFMA GEMM (verified R11/R12), optional fused attention logits ----------------
template<int K, int KP, int EPI, int OUTBF16, int HPT>
__global__ void __launch_bounds__(256, 4)
k_gemm(const float* __restrict__ A, const ushort_t* __restrict__ BT,
       const float* __restrict__ bias, void* __restrict__ Cmat,
       int N, int HC,
       const float* __restrict__ a_s, const float* __restrict__ a_d,
       float* __restrict__ es, float* __restrict__ ed){
    int t = threadIdx.x;
    int w = t >> 6, lane = t & 63;
    int lr = lane & 15, lk = lane >> 4;
    int row0 = blockIdx.x*64, col0 = blockIdx.y*64;
    int row = row0 + w*16 + lr;

    f32x4 acc[4];
    #pragma unroll
    for(int f=0; f<4; f++) acc[f] = (f32x4){0.f,0.f,0.f,0.f};

    #pragma unroll
    for(int kb = 0; kb < K; kb += 32){
        int k0 = kb + lk*8;
        short8 af = {0,0,0,0,0,0,0,0};
        if(row < N && k0 < K){
            const float* ap = &A[(size_t)row*K + k0];
            float4 a0 = *(const float4*)ap;
            float4 a1 = *(const float4*)(ap + 4);
            af[0]=(short)f2bu(a0.x); af[1]=(short)f2bu(a0.y);
            af[2]=(short)f2bu(a0.z); af[3]=(short)f2bu(a0.w);
            af[4]=(short)f2bu(a1.x); af[5]=(short)f2bu(a1.y);
            af[6]=(short)f2bu(a1.z); af[7]=(short)f2bu(a1.w);
        }
        #pragma unroll
        for(int f=0; f<4; f++){
            int col = col0 + f*16 + lr;
            short8 bf = *(const short8*)&BT[(size_t)col*KP + k0];
            acc[f] = __builtin_amdgcn_mfma_f32_16x16x32_bf16(af, bf, acc[f], 0, 0, 0);
        }
    }

    #pragma unroll
    for(int f=0; f<4; f++){
        #pragma unroll
        for(int j=0; j<4; j++){
            int r = row0 + w*16 + lk*4 + j;
            if(r >= N) continue;
            int col = col0 + f*16 + lr;
            float v = acc[f][j];
            if(EPI){
                v += bias[col];
                v = v>0.f ? v : expm1f(v);
            }
            if(OUTBF16) ((ushort_t*)Cmat)[(size_t)r*HC + col] = f2bu(v);
            else        ((float*)Cmat)[(size_t)r*HC + col] = v;
        }
    }

    if constexpr (HPT > 0){
        constexpr int CH = 64/HPT;
        #pragma unroll
        for(int j=0; j<4; j++){
            int r = row0 + w*16 + lk*4 + j;
            float sp[HPT], dp[HPT];
            #pragma unroll
            for(int g=0; g<HPT; g++){ sp[g]=0.f; dp[g]=0.f; }
            #pragma unroll
            for(int f=0; f<4; f++){
                float vb = bu2f(f2bu(acc[f][j]));
                int g   = (HPT==2) ? (f>>1) : 0;
                int cih = (HPT==2) ? ((f&1)*16 + lr) : (f*16 + lr);
                int ai  = col0 + g*CH + cih;
                sp[g] += vb * a_s[ai];
                dp[g] += vb * a_d[ai];
            }
            #pragma unroll
            for(int st=1; st<16; st<<=1){
                #pragma unroll
                for(int g=0; g<HPT; g++){
                    sp[g] += __shfl_xor(sp[g], st, 64);
                    dp[g] += __shfl_xor(dp[g], st, 64);
                }
            }
            if(lr == 0 && r < N){
                #pragma unroll
                for(int g=0; g<HPT; g++){
                    int head = col0/CH + g;
                    es[r*NHEADS + head] = sp[g];
                    ed[r*NHEADS + head] = dp[g];
                }
            }
        }
    }
}

// ---------------- attention logits (layer 3 only): 4 threads per (n,h) ----------------
template<int C>
__global__ void k_attn(const ushort_t* hf, const float* a_s, const float* a_d,
                       float* es, float* ed, int N){
    int tid = blockIdx.x*blockDim.x + threadIdx.x;
    if(tid >= N*NHEADS*4) return;
    int q   = tid & 3;
    int idx = tid >> 2;
    int n = idx/NHEADS, h = idx%NHEADS;
    constexpr int CQ = C/4;
    const ushort_t* hp = hf + (size_t)n*NHEADS*C + h*C + q*CQ;
    const float* asp = a_s + h*C + q*CQ;
    const float* adp = a_d + h*C + q*CQ;
    float s=0.f, d=0.f;
    #pragma unroll
    for(int cb=0; cb<CQ/8; cb++){
        uint4 qv = *(const uint4*)(hp + cb*8);
        uint_t uu[4] = {qv.x, qv.y, qv.z, qv.w};
        #pragma unroll
        for(int j=0;j<4;j++){
            float f0 = __uint_as_float(uu[j]<<16);
            float f1 = __uint_as_float(uu[j] & 0xFFFF0000u);
            int c = cb*8 + j*2;
            s += f0*asp[c] + f1*asp[c+1];
            d += f0*adp[c] + f1*adp[c+1];
        }
    }
    s += __shfl_xor(s, 1, 64); s += __shfl_xor(s, 2, 64);
    d += __shfl_xor(d, 1, 64); d += __shfl_xor(d, 2, 64);
    if(q == 0){ es[idx]=s; ed[idx]=d; }
}

// ---------------- fused softmax + aggregation, srcs-in-LDS + 2-deep pipelined gather ----------------
template<int C>
__global__ void __launch_bounds__(256, 4)
k_fused(const int* __restrict__ indptr, const int* __restrict__ srcs,
        const float* __restrict__ es, const float* __restrict__ ed,
        const ushort_t* __restrict__ hf, const float* __restrict__ bc,
        float* __restrict__ out, int N)
{
    __shared__ float wlds[4][64*NHEADS];
    __shared__ float stat[4][NHEADS];
    __shared__ int   slds4[4][64];
    __shared__ int   degs[4];
    int wslot = threadIdx.x >> 6;
    int lane  = threadIdx.x & 63;
    int n = (blockIdx.x << 2) + wslot;
    bool valid = (n < N);
    int p0 = 0, deg = 0;
    if(valid){ p0 = indptr[n]; deg = indptr[n+1] - p0; }
    if(lane == 0) degs[wslot] = deg;
    if(valid && lane < deg && lane < 64) slds4[wslot][lane] = srcs[p0+lane];
    __syncthreads();
    int maxdeg = max(max(degs[0],degs[1]), max(degs[2],degs[3]));
    int nch = (maxdeg + 63) >> 6;
    float* wl = wlds[wslot];
    const int* sl = slds4[wslot];

    int e6 = lane/10, h6 = lane%10;
    float edv = (valid && lane < 60) ? ed[n*NHEADS + h6] : 0.f;

    // ---- pass A: w = exp(leaky(e)) into LDS; den accumulated in-flight, folded via shfl ----
    float denp = 0.f;
    for(int c = 0; c < nch; c++){
        int base = c << 6;
        int lim = deg - base; if(lim > 64) lim = 64; if(lim < 0) lim = 0;
        if(valid && lane < 60){
            for(int i = e6; i < lim; i += 6){
                int sv = (c == 0) ? sl[i] : srcs[p0+base+i];
                float v = es[(size_t)sv*NHEADS + h6] + edv;
                v = (v >= 0.f) ? v : 0.2f*v;
                float wv = expf(fminf(v, 60.f));
                wl[i*NHEADS + h6] = wv;
                denp += wv;
            }
        }
        __syncthreads();
    }
    float tA = __shfl(denp, lane+30, 64);
    if(lane < 30) denp += tA;
    float tB = __shfl(denp, lane+10, 64);
    float tC = __shfl(denp, lane+20, 64);
    if(lane < 10) denp += tB + tC;
    if(valid && lane < NHEADS) stat[wslot][lane] = 1.f/(denp + 1e-30f);
    __syncthreads();
    // ---- normalize weights in LDS (nch==1 fast path; fallback normalizes on the fly) ----
    if(nch == 1 && valid && lane < 60){
        float dv = stat[wslot][h6];
        for(int i = e6; i < deg; i += 6) wl[i*NHEADS + h6] *= dv;
    }
    __syncthreads();

    constexpr int TPN = C/8;
    constexpr int EG  = 64/TPN;
    int local = lane % TPN, eg = lane / TPN;
    int c8 = local*8;
    float acc[8];
    #pragma unroll
    for(int i=0;i<8;i++) acc[i]=0.f;

    if(nch == 1){
        // ---- 2-deep pipelined gather: srcs from LDS, weights pre-normalized ----
        int lim = deg;
        uint4 qA[NHEADS], qB[NHEADS];
        auto loadQ = [&](uint4* q, int idx){
            const ushort_t* hp = hf + (size_t)sl[idx]*NHEADS*C + c8;
            #pragma unroll
            for(int h=0;h<NHEADS;h++) q[h] = *(const uint4*)(hp + h*C);
        };
        auto consume = [&](uint4* q, int idx){
            const float* wp = &wl[idx*NHEADS];
            #pragma unroll
            for(int h=0;h<NHEADS;h++){
                float wd = wp[h];
                acc[0] += wd * __uint_as_float(q[h].x<<16);
                acc[1] += wd * __uint_as_float(q[h].x & 0xFFFF0000u);
                acc[2] += wd * __uint_as_float(q[h].y<<16);
                acc[3] += wd * __uint_as_float(q[h].y & 0xFFFF0000u);
                acc[4] += wd * __uint_as_float(q[h].z<<16);
                acc[5] += wd * __uint_as_float(q[h].z & 0xFFFF0000u);
                acc[6] += wd * __uint_as_float(q[h].w<<16);
                acc[7] += wd * __uint_as_float(q[h].w & 0xFFFF0000u);
            }
        };
        int i = eg;
        if(i < lim){
            loadQ(qA, i);
            while(true){
                int j = i + EG;
                if(j < lim) loadQ(qB, j);
                consume(qA, i);
                if(j >= lim) break;
                int k2 = j + EG;
                if(k2 < lim) loadQ(qA, k2);
                consume(qB, j);
                if(k2 >= lim) break;
                i = k2;
            }
        }
    } else {
        // ---- fallback chunked path (deg > 64; statistically never) ----
        float dinv_r[NHEADS];
        #pragma unroll
        for(int h=0; h<NHEADS; h++) dinv_r[h] = stat[wslot][h];
        for(int c = 0; c < nch; c++){
            int base = c << 6;
            int lim = deg - base; if(lim > 64) lim = 64; if(lim < 0) lim = 0;
            if(valid && lane < 60){
                for(int i = e6; i < lim; i += 6){
                    float v = es[(size_t)srcs[p0+base+i]*NHEADS + h6] + edv;
                    v = (v >= 0.f) ? v : 0.2f*v;
                    wl[i*NHEADS + h6] = expf(fminf(v, 60.f));
                }
            }
            __syncthreads();
            if(valid){
                for(int i = eg; i < lim; i += EG){
                    int s = srcs[p0+base+i];
                    const ushort_t* hp = hf + (size_t)s*NHEADS*C + c8;
                    const float* wp = &wl[i*NHEADS];
                    #pragma unroll
                    for(int h=0;h<NHEADS;h++){
                        uint4 q = *(const uint4*)(hp + h*C);
                        float wd = wp[h]*dinv_r[h];
                        acc[0] += wd * __uint_as_float(q.x<<16);
                        acc[1] += wd * __uint_as_float(q.x & 0xFFFF0000u);
                        acc[2] += wd * __uint_as_float(q.y<<16);
                        acc[3] += wd * __uint_as_float(q.y & 0xFFFF0000u);
                        acc[4] += wd * __uint_as_float(q.z<<16);
                        acc[5] += wd * __uint_as_float(q.z & 0xFFFF0000u);
                        acc[6] += wd * __uint_as_float(q.w<<16);
                        acc[7] += wd * __uint_as_float(q.w & 0xFFFF0000u);
                    }
                }
            }
            __syncthreads();
        }
    }

    #pragma unroll
    for(int s = TPN; s < 64; s <<= 1){
        #pragma unroll
        for(int i=0;i<8;i++) acc[i] += __shfl_xor(acc[i], s, 64);
    }
    if(valid && eg == 0){
        float4 v0, v1;
        #pragma unroll
        for(int i=0;i<8;i++){
            float v = acc[i]*(1.f/NHEADS) + bc[c8+i];
            v = v>0.f ? v : expm1f(v);
            if(i<4) ((float*)&v0)[i] = v; else ((float*)&v1)[i-4] = v;
        }
        *(float4*)&out[(size_t)n*C + c8]     = v0;
        *(float4*)&out[(size_t)n*C + c8 + 4] = v1;
    }
}

// ---------------- head: logits 256->24 + log_softmax ----------------
__global__ void k_head(const float* hin, const float* W2, const float* b2v, float* out, int N){
    int grp  = threadIdx.x/32;
    int lane = threadIdx.x%32;
    int n = blockIdx.x*8 + grp;
    if(n>=N) return;
    float acc = -1e30f;
    if(lane < 24){
        acc = b2v[lane];
        for(int k=0;k<256;k++) acc += hin[n*256+k]*W2[k*24+lane];
    }
    float mx = acc;
    for(int off=16; off; off>>=1) mx = fmaxf(mx, __shfl_xor(mx, off, 32));
    float ex = (lane<24)? expf(acc-mx) : 0.f;
    float sm = ex;
    for(int off=16; off; off>>=1) sm += __shfl_xor(sm, off, 32);
    if(lane<24) out[n*24+lane] = acc - mx - logf(sm);
}

extern "C" void kernel_launch(void* const* d_in, const int* in_sizes, int n_in,
                              void* d_out, int out_size, void* d_ws, size_t ws_size,
                              hipStream_t stream) {
    const float* x   = (const float*)d_in[0];
    const int*  eidx = (const int*)d_in[1];
    const float* W0 = (const float*)d_in[3];  const float* b0 = (const float*)d_in[4];
    const float* Wc1= (const float*)d_in[5];  const float* as1= (const float*)d_in[6];
    const float* ad1= (const float*)d_in[7];  const float* bc1= (const float*)d_in[8];
    const float* Wc2= (const float*)d_in[9];  const float* as2= (const float*)d_in[10];
    const float* ad2= (const float*)d_in[11]; const float* bc2= (const float*)d_in[12];
    const float* Wc3= (const float*)d_in[13]; const float* as3= (const float*)d_in[14];
    const float* ad3= (const float*)d_in[15]; const float* bc3= (const float*)d_in[16];
    const float* W1 = (const float*)d_in[17]; const float* b1 = (const float*)d_in[18];
    const float* W2 = (const float*)d_in[19]; const float* b2 = (const float*)d_in[20];
    float* out = (float*)d_out;

    const int N  = in_sizes[0]/24;
    const int E  = in_sizes[1]/2;
    const int ET = E + N;

    char* w = (char*)d_ws;
    size_t off = 0;
    auto alloc = [&](size_t bytes)->void* {
        void* p = w + off;
        off = (off + bytes + 255) & ~(size_t)255;
        return p;
    };
    int*   cnt    = (int*)  alloc((size_t)N*4);
    int*   indptr = (int*)  alloc((size_t)(N+1)*4);
    int*   srcs   = (int*)  alloc((size_t)ET*4);
    float* es     = (float*)alloc((size_t)N*NHEADS*4);
    float* ed     = (float*)alloc((size_t)N*NHEADS*4);
    float* nfA    = (float*)alloc((size_t)N*256*4);
    float* nfB    = (float*)alloc((size_t)N*256*4);
    ushort_t* hf  = (ushort_t*)alloc((size_t)N*1280*2);
    ushort_t* WT1 = (ushort_t*)alloc((size_t)320*32*2);
    ushort_t* WT2 = (ushort_t*)alloc((size_t)640*32*2);
    ushort_t* WT3 = (ushort_t*)alloc((size_t)1280*64*2);
    ushort_t* WT4 = (ushort_t*)alloc((size_t)256*128*2);

    // setup: memset + (transposes | fc0 | CSR count) in one dispatch
    hipMemsetAsync(cnt, 0, (size_t)N*4, stream);
    int setupWork = 145408 + N*16 + ET;
    k_setup<<<(setupWork+255)/256,256,0,stream>>>(Wc1, Wc2, Wc3, W1, WT1, WT2, WT3, WT4,
                                                  x, W0, b0, nfA, eidx, cnt, E, N);
    k_scan <<<1,1024,0,stream>>>(cnt, N, ET, indptr);
    int gE = (ET+255)/256;
    k_fill <<<gE,256,0,stream>>>(eidx, E, N, cnt, srcs);
    k_sortw<<<((size_t)N*64+255)/256,256,0,stream>>>(indptr, srcs, N);

    int gRow = (N+63)/64;
    int gNode = (N+3)/4;
    int gA   = (N*NHEADS*4+255)/256;

    // GAT1: 16 -> H x 32  (attn fused in gemm epilogue, HPT=2)
    k_gemm<16,32,0,1,2><<<dim3(gRow,320/64),256,0,stream>>>(nfA, WT1, nullptr, hf, N, 320, as1, ad1, es, ed);
    k_fused<32><<<gNode,256,0,stream>>>(indptr, srcs, es, ed, hf, bc1, nfB, N);

    // GAT2: 32 -> H x 64  (attn fused, HPT=1)
    k_gemm<32,32,0,1,1><<<dim3(gRow,640/64),256,0,stream>>>(nfB, WT2, nullptr, hf, N, 640, as2, ad2, es, ed);
    k_fused<64><<<gNode,256,0,stream>>>(indptr, srcs, es, ed, hf, bc2, nfA, N);

    // GAT3: 64 -> H x 128 (tile=half head -> separate attn kernel)
    k_gemm<64,64,0,1,0><<<dim3(gRow,1280/64),256,0,stream>>>(nfA, WT3, nullptr, hf, N, 1280, nullptr, nullptr, nullptr, nullptr);
    k_attn<128><<<gA,256,0,stream>>>(hf, as3, ad3, es, ed, N);
    k_fused<128><<<gNode,256,0,stream>>>(indptr, srcs, es, ed, hf, bc3, nfB, N);

    // fc1: [N,128]@[128,256] + bias + ELU (f32 out)
    k_gemm<128,128,1,0,0><<<dim3(gRow,256/64),256,0,stream>>>(nfB, WT4, b1, nfA, N, 256, nullptr, nullptr, nullptr, nullptr);
    // head
    k_head<<<(N+7)/8,256,0,stream>>>(nfA, W2, b2, out, N);
}

// Round 18
// 277.911 us; speedup vs baseline: 1.6273x; 1.6273x over previous
//
#include <hip/hip_runtime.h>
#include <hip/hip_bf16.h>
#include <math.h>

#define NHEADS 10

typedef unsigned short ushort_t;
typedef unsigned int uint_t;

typedef __attribute__((ext_vector_type(4))) float f32x4;
typedef __attribute__((ext_vector_type(8))) short short8;

__device__ __forceinline__ float bu2f(ushort_t u){ return __uint_as_float(((uint_t)u)<<16); }
__device__ __forceinline__ ushort_t f2bu(float f){
    uint_t b = __float_as_uint(f);
    return (ushort_t)((b + 0x7FFFu + ((b>>16)&1u)) >> 16);   // RNE
}

// ---------------- CSR scan ----------------
__global__ void k_scan(int* cnt, int N, int ET, int* indptr){
    __shared__ int lds[1024];
    int t = threadIdx.x;
    int chunk = (N + 1023)/1024;
    int base = t*chunk;
    int s = 0;
    for(int i=0;i<chunk;i++){ int idx=base+i; if(idx<N) s += cnt[idx]; }
    lds[t]=s;
    __syncthreads();
    for(int off=1; off<1024; off<<=1){
        int v = (t>=off)? lds[t-off] : 0;
        __syncthreads();
        lds[t]+=v;
        __syncthreads();
    }
    int run = lds[t]-s;
    for(int i=0;i<chunk;i++){
        int idx=base+i;
        if(idx<N){
            int c = cnt[idx];
            indptr[idx]=run;
            cnt[idx]=run;
            run += c;
        }
    }
    if(t==0) indptr[N]=ET;
}

__global__ void k_fill(const int* eidx, int E, int N, int* cursor, int* srcs){
    int e = blockIdx.x*blockDim.x + threadIdx.x;
    int ET = E + N;
    if(e >= ET) return;
    int s, d;
    if(e < E){ s = eidx[e]; d = eidx[E+e]; } else { s = e-E; d = e-E; }
    int pos = atomicAdd(&cursor[d], 1);
    srcs[pos] = s;
}

// wave-parallel bitonic sort of each node's src segment (1 wave / node)
__global__ void k_sortw(const int* indptr, int* srcs, int N){
    int wid  = (blockIdx.x*blockDim.x + threadIdx.x) >> 6;
    int lane = threadIdx.x & 63;
    if(wid >= N) return;
    int p0 = indptr[wid], p1 = indptr[wid+1];
    int deg = p1 - p0;
    if(deg <= 1) return;
    if(deg <= 64){
        int v = (lane < deg) ? srcs[p0+lane] : 0x7FFFFFFF;
        #pragma unroll
        for(int k=2; k<=64; k<<=1){
            #pragma unroll
            for(int j=k>>1; j>0; j>>=1){
                int partner = __shfl_xor(v, j, 64);
                bool dir   = ((lane & k) == 0);
                bool small = ((lane & j) == 0);
                int mn = min(v, partner), mx = max(v, partner);
                v = (dir == small) ? mn : mx;
            }
        }
        if(lane < deg) srcs[p0+lane] = v;
    } else if(lane == 0){               // safety fallback, statistically never
        for(int i=p0+1;i<p1;i++){
            int v2 = srcs[i]; int j=i-1;
            while(j>=p0 && srcs[j]>v2){ srcs[j+1]=srcs[j]; j--; }
            srcs[j+1]=v2;
        }
    }
}

// ---------------- setup: weight transposes + fc0 + CSR count, one dispatch ----------------
__global__ void k_setup(const float* __restrict__ W1c,const float* __restrict__ W2c,
                        const float* __restrict__ W3c,const float* __restrict__ W4c,
                        ushort_t* T1,ushort_t* T2,ushort_t* T3,ushort_t* T4,
                        const float* __restrict__ x, const float* __restrict__ W0,
                        const float* __restrict__ b0, float* __restrict__ fc0o,
                        const int* __restrict__ eidx, int* cnt, int E, int N){
    int idx = blockIdx.x*blockDim.x + threadIdx.x;
    if(idx < 10240){ int c=idx/32, k=idx%32; T1[idx] = (k<16)? f2bu(W1c[(size_t)k*320+c]) : (ushort_t)0; return; }
    idx -= 10240;
    if(idx < 20480){ int c=idx/32, k=idx%32; T2[idx] = f2bu(W2c[(size_t)k*640+c]); return; }
    idx -= 20480;
    if(idx < 81920){ int c=idx/64, k=idx%64; T3[idx] = f2bu(W3c[(size_t)k*1280+c]); return; }
    idx -= 81920;
    if(idx < 32768){ int c=idx/128, k=idx%128; T4[idx] = f2bu(W4c[(size_t)k*256+c]); return; }
    idx -= 32768;
    if(idx < N*16){
        int n = idx>>4, c = idx&15;
        float acc = b0[c];
        #pragma unroll
        for(int k=0;k<24;k++) acc += x[n*24+k] * W0[k*16+c];
        fc0o[idx] = acc>0.f ? acc : expm1f(acc);
        return;
    }
    idx -= N*16;
    if(idx < E+N){
        int d = (idx < E) ? eidx[E + idx] : (idx - E);
        atomicAdd(&cnt[d], 1);
    }
}

// ---------------- LDS-free MFMA GEMM (verified R11/R12), optional fused attention logits ----------------
// HPT: 2 = two heads per 64-col tile (C=32), 1 = one head (C=64),
//      -1 = half-head per tile with 2-way atomicAdd partials (C=128), 0 = none.
template<int K, int KP, int EPI, int OUTBF16, int HPT>
__global__ void __launch_bounds__(256, 4)
k_gemm(const float* __restrict__ A, const ushort_t* __restrict__ BT,
       const float* __restrict__ bias, void* __restrict__ Cmat,
       int N, int HC,
       const float* __restrict__ a_s, const float* __restrict__ a_d,
       float* __restrict__ es, float* __restrict__ ed){
    int t = threadIdx.x;
    int w = t >> 6, lane = t & 63;
    int lr = lane & 15, lk = lane >> 4;
    int row0 = blockIdx.x*64, col0 = blockIdx.y*64;
    int row = row0 + w*16 + lr;

    f32x4 acc[4];
    #pragma unroll
    for(int f=0; f<4; f++) acc[f] = (f32x4){0.f,0.f,0.f,0.f};

    #pragma unroll
    for(int kb = 0; kb < K; kb += 32){
        int k0 = kb + lk*8;
        short8 af = {0,0,0,0,0,0,0,0};
        if(row < N && k0 < K){
            const float* ap = &A[(size_t)row*K + k0];
            float4 a0 = *(const float4*)ap;
            float4 a1 = *(const float4*)(ap + 4);
            af[0]=(short)f2bu(a0.x); af[1]=(short)f2bu(a0.y);
            af[2]=(short)f2bu(a0.z); af[3]=(short)f2bu(a0.w);
            af[4]=(short)f2bu(a1.x); af[5]=(short)f2bu(a1.y);
            af[6]=(short)f2bu(a1.z); af[7]=(short)f2bu(a1.w);
        }
        #pragma unroll
        for(int f=0; f<4; f++){
            int col = col0 + f*16 + lr;
            short8 bf = *(const short8*)&BT[(size_t)col*KP + k0];
            acc[f] = __builtin_amdgcn_mfma_f32_16x16x32_bf16(af, bf, acc[f], 0, 0, 0);
        }
    }

    #pragma unroll
    for(int f=0; f<4; f++){
        #pragma unroll
        for(int j=0; j<4; j++){
            int r = row0 + w*16 + lk*4 + j;
            if(r >= N) continue;
            int col = col0 + f*16 + lr;
            float v = acc[f][j];
            if(EPI){
                v += bias[col];
                v = v>0.f ? v : expm1f(v);
            }
            if(OUTBF16) ((ushort_t*)Cmat)[(size_t)r*HC + col] = f2bu(v);
            else        ((float*)Cmat)[(size_t)r*HC + col] = v;
        }
    }

    if constexpr (HPT > 0){
        constexpr int CH = 64/HPT;
        #pragma unroll
        for(int j=0; j<4; j++){
            int r = row0 + w*16 + lk*4 + j;
            float sp[HPT], dp[HPT];
            #pragma unroll
            for(int g=0; g<HPT; g++){ sp[g]=0.f; dp[g]=0.f; }
            #pragma unroll
            for(int f=0; f<4; f++){
                float vb = bu2f(f2bu(acc[f][j]));
                int g   = (HPT==2) ? (f>>1) : 0;
                int cih = (HPT==2) ? ((f&1)*16 + lr) : (f*16 + lr);
                int ai  = col0 + g*CH + cih;
                sp[g] += vb * a_s[ai];
                dp[g] += vb * a_d[ai];
            }
            #pragma unroll
            for(int st=1; st<16; st<<=1){
                #pragma unroll
                for(int g=0; g<HPT; g++){
                    sp[g] += __shfl_xor(sp[g], st, 64);
                    dp[g] += __shfl_xor(dp[g], st, 64);
                }
            }
            if(lr == 0 && r < N){
                #pragma unroll
                for(int g=0; g<HPT; g++){
                    int head = col0/CH + g;
                    es[r*NHEADS + head] = sp[g];
                    ed[r*NHEADS + head] = dp[g];
                }
            }
        }
    }
    if constexpr (HPT == -1){
        // C=128: 64-col tile = half a head. Two commutative atomicAdds per (n,h) -> deterministic.
        int head = col0 >> 7;              // col0/128
        #pragma unroll
        for(int j=0; j<4; j++){
            int r = row0 + w*16 + lk*4 + j;
            float sp=0.f, dp=0.f;
            #pragma unroll
            for(int f=0; f<4; f++){
                float vb = bu2f(f2bu(acc[f][j]));
                int ai = (head<<7) + (col0 & 127) + f*16 + lr;   // [h][c] flat, c within head
                sp += vb * a_s[ai];
                dp += vb * a_d[ai];
            }
            #pragma unroll
            for(int st=1; st<16; st<<=1){
                sp += __shfl_xor(sp, st, 64);
                dp += __shfl_xor(dp, st, 64);
            }
            if(lr == 0 && r < N){
                atomicAdd(&es[r*NHEADS + head], sp);
                atomicAdd(&ed[r*NHEADS + head], dp);
            }
        }
    }
}

// ---------------- fused softmax + aggregation (R16 structure, float2 weight reads) ----------------
template<int C>
__global__ void __launch_bounds__(256, 4)
k_fused(const int* __restrict__ indptr, const int* __restrict__ srcs,
        const float* __restrict__ es, const float* __restrict__ ed,
        const ushort_t* __restrict__ hf, const float* __restrict__ bc,
        float* __restrict__ out, int N)
{
    __shared__ float wlds[4][64*NHEADS];
    __shared__ float stat[4][NHEADS];
    __shared__ int   degs[4];
    int wslot = threadIdx.x >> 6;
    int lane  = threadIdx.x & 63;
    int n = (blockIdx.x << 2) + wslot;
    bool valid = (n < N);
    int p0 = 0, deg = 0;
    if(valid){ p0 = indptr[n]; deg = indptr[n+1] - p0; }
    if(lane == 0) degs[wslot] = deg;
    __syncthreads();
    int maxdeg = max(max(degs[0],degs[1]), max(degs[2],degs[3]));
    int nch = (maxdeg + 63) >> 6;
    float* wl = wlds[wslot];

    int e6 = lane/10, h6 = lane%10;
    float edv = (valid && lane < 60) ? ed[n*NHEADS + h6] : 0.f;

    // ---- pass A: w = exp(leaky(e)) into LDS; den accumulated during fill, folded via shfl ----
    float denp = 0.f;
    for(int c = 0; c < nch; c++){
        int base = c << 6;
        int lim = deg - base; if(lim > 64) lim = 64; if(lim < 0) lim = 0;
        if(valid && lane < 60){
            for(int i = e6; i < lim; i += 6){
                float v = es[(size_t)srcs[p0+base+i]*NHEADS + h6] + edv;
                v = (v >= 0.f) ? v : 0.2f*v;
                float wv = expf(fminf(v, 60.f));
                wl[i*NHEADS + h6] = wv;
                denp += wv;
            }
        }
        __syncthreads();
    }
    float tA = __shfl(denp, lane+30, 64);
    if(lane < 30) denp += tA;
    float tB = __shfl(denp, lane+10, 64);
    float tC = __shfl(denp, lane+20, 64);
    if(lane < 10) denp += tB + tC;
    if(valid && lane < NHEADS) stat[wslot][lane] = 1.f/(denp + 1e-30f);
    __syncthreads();
    // normalize weights in LDS (nch==1 fast path)
    if(nch == 1 && valid && lane < 60){
        float dv = stat[wslot][h6];
        for(int i = e6; i < deg; i += 6) wl[i*NHEADS + h6] *= dv;
    }
    __syncthreads();

    constexpr int TPN = C/8;
    constexpr int EG  = 64/TPN;
    int local = lane % TPN, eg = lane / TPN;
    int c8 = local*8;
    float acc[8];
    #pragma unroll
    for(int i=0;i<8;i++) acc[i]=0.f;

    if(nch == 1){
        for(int i = eg; i < deg; i += EG){
            int s = srcs[p0+i];
            const ushort_t* hp = hf + (size_t)s*NHEADS*C + c8;
            const float2* wp2 = (const float2*)&wl[i*NHEADS];   // 8B-aligned (stride 40B)
            #pragma unroll
            for(int hh=0; hh<5; hh++){
                float2 wv = wp2[hh];
                uint4 q0 = *(const uint4*)(hp + (2*hh)*C);
                uint4 q1 = *(const uint4*)(hp + (2*hh+1)*C);
                float w0 = wv.x, w1 = wv.y;
                acc[0] += w0 * __uint_as_float(q0.x<<16) + w1 * __uint_as_float(q1.x<<16);
                acc[1] += w0 * __uint_as_float(q0.x & 0xFFFF0000u) + w1 * __uint_as_float(q1.x & 0xFFFF0000u);
                acc[2] += w0 * __uint_as_float(q0.y<<16) + w1 * __uint_as_float(q1.y<<16);
                acc[3] += w0 * __uint_as_float(q0.y & 0xFFFF0000u) + w1 * __uint_as_float(q1.y & 0xFFFF0000u);
                acc[4] += w0 * __uint_as_float(q0.z<<16) + w1 * __uint_as_float(q1.z<<16);
                acc[5] += w0 * __uint_as_float(q0.z & 0xFFFF0000u) + w1 * __uint_as_float(q1.z & 0xFFFF0000u);
                acc[6] += w0 * __uint_as_float(q0.w<<16) + w1 * __uint_as_float(q1.w<<16);
                acc[7] += w0 * __uint_as_float(q0.w & 0xFFFF0000u) + w1 * __uint_as_float(q1.w & 0xFFFF0000u);
            }
        }
    } else {
        // fallback chunked path (deg > 64; statistically never)
        float dinv_r[NHEADS];
        #pragma unroll
        for(int h=0; h<NHEADS; h++) dinv_r[h] = stat[wslot][h];
        for(int c = 0; c < nch; c++){
            int base = c << 6;
            int lim = deg - base; if(lim > 64) lim = 64; if(lim < 0) lim = 0;
            if(valid && lane < 60){
                for(int i = e6; i < lim; i += 6){
                    float v = es[(size_t)srcs[p0+base+i]*NHEADS + h6] + edv;
                    v = (v >= 0.f) ? v : 0.2f*v;
                    wl[i*NHEADS + h6] = expf(fminf(v, 60.f));
                }
            }
            __syncthreads();
            if(valid){
                for(int i = eg; i < lim; i += EG){
                    int s = srcs[p0+base+i];
                    const ushort_t* hp = hf + (size_t)s*NHEADS*C + c8;
                    const float* wp = &wl[i*NHEADS];
                    #pragma unroll
                    for(int h=0;h<NHEADS;h++){
                        uint4 q = *(const uint4*)(hp + h*C);
                        float wd = wp[h]*dinv_r[h];
                        acc[0] += wd * __uint_as_float(q.x<<16);
                        acc[1] += wd * __uint_as_float(q.x & 0xFFFF0000u);
                        acc[2] += wd * __uint_as_float(q.y<<16);
                        acc[3] += wd * __uint_as_float(q.y & 0xFFFF0000u);
                        acc[4] += wd * __uint_as_float(q.z<<16);
                        acc[5] += wd * __uint_as_float(q.z & 0xFFFF0000u);
                        acc[6] += wd * __uint_as_float(q.w<<16);
                        acc[7] += wd * __uint_as_float(q.w & 0xFFFF0000u);
                    }
                }
            }
            __syncthreads();
        }
    }

    #pragma unroll
    for(int s = TPN; s < 64; s <<= 1){
        #pragma unroll
        for(int i=0;i<8;i++) acc[i] += __shfl_xor(acc[i], s, 64);
    }
    if(valid && eg == 0){
        float4 v0, v1;
        #pragma unroll
        for(int i=0;i<8;i++){
            float v = acc[i]*(1.f/NHEADS) + bc[c8+i];
            v = v>0.f ? v : expm1f(v);
            if(i<4) ((float*)&v0)[i] = v; else ((float*)&v1)[i-4] = v;
        }
        *(float4*)&out[(size_t)n*C + c8]     = v0;
        *(float4*)&out[(size_t)n*C + c8 + 4] = v1;
    }
}

// ---------------- head: logits 256->24 + log_softmax ----------------
__global__ void k_head(const float* hin, const float* W2, const float* b2v, float* out, int N){
    int grp  = threadIdx.x/32;
    int lane = threadIdx.x%32;
    int n = blockIdx.x*8 + grp;
    if(n>=N) return;
    float acc = -1e30f;
    if(lane < 24){
        acc = b2v[lane];
        for(int k=0;k<256;k++) acc += hin[n*256+k]*W2[k*24+lane];
    }
    float mx = acc;
    for(int off=16; off; off>>=1) mx = fmaxf(mx, __shfl_xor(mx, off, 32));
    float ex = (lane<24)? expf(acc-mx) : 0.f;
    float sm = ex;
    for(int off=16; off; off>>=1) sm += __shfl_xor(sm, off, 32);
    if(lane<24) out[n*24+lane] = acc - mx - logf(sm);
}

extern "C" void kernel_launch(void* const* d_in, const int* in_sizes, int n_in,
                              void* d_out, int out_size, void* d_ws, size_t ws_size,
                              hipStream_t stream) {
    const float* x   = (const float*)d_in[0];
    const int*  eidx = (const int*)d_in[1];
    const float* W0 = (const float*)d_in[3];  const float* b0 = (const float*)d_in[4];
    const float* Wc1= (const float*)d_in[5];  const float* as1= (const float*)d_in[6];
    const float* ad1= (const float*)d_in[7];  const float* bc1= (const float*)d_in[8];
    const float* Wc2= (const float*)d_in[9];  const float* as2= (const float*)d_in[10];
    const float* ad2= (const float*)d_in[11]; const float* bc2= (const float*)d_in[12];
    const float* Wc3= (const float*)d_in[13]; const float* as3= (const float*)d_in[14];
    const float* ad3= (const float*)d_in[15]; const float* bc3= (const float*)d_in[16];
    const float* W1 = (const float*)d_in[17]; const float* b1 = (const float*)d_in[18];
    const float* W2 = (const float*)d_in[19]; const float* b2 = (const float*)d_in[20];
    float* out = (float*)d_out;

    const int N  = in_sizes[0]/24;
    const int E  = in_sizes[1]/2;
    const int ET = E + N;

    char* w = (char*)d_ws;
    size_t off = 0;
    auto alloc = [&](size_t bytes)->void* {
        void* p = w + off;
        off = (off + bytes + 255) & ~(size_t)255;
        return p;
    };
    int*   cnt    = (int*)  alloc((size_t)N*4);
    int*   indptr = (int*)  alloc((size_t)(N+1)*4);
    int*   srcs   = (int*)  alloc((size_t)ET*4);
    float* es     = (float*)alloc((size_t)N*NHEADS*4);
    float* ed     = (float*)alloc((size_t)N*NHEADS*4);
    float* nfA    = (float*)alloc((size_t)N*256*4);
    float* nfB    = (float*)alloc((size_t)N*256*4);
    ushort_t* hf  = (ushort_t*)alloc((size_t)N*1280*2);
    ushort_t* WT1 = (ushort_t*)alloc((size_t)320*32*2);
    ushort_t* WT2 = (ushort_t*)alloc((size_t)640*32*2);
    ushort_t* WT3 = (ushort_t*)alloc((size_t)1280*64*2);
    ushort_t* WT4 = (ushort_t*)alloc((size_t)256*128*2);

    // setup: memset + (transposes | fc0 | CSR count) in one dispatch
    hipMemsetAsync(cnt, 0, (size_t)N*4, stream);
    int setupWork = 145408 + N*16 + ET;
    k_setup<<<(setupWork+255)/256,256,0,stream>>>(Wc1, Wc2, Wc3, W1, WT1, WT2, WT3, WT4,
                                                  x, W0, b0, nfA, eidx, cnt, E, N);
    k_scan <<<1,1024,0,stream>>>(cnt, N, ET, indptr);
    int gE = (ET+255)/256;
    k_fill <<<gE,256,0,stream>>>(eidx, E, N, cnt, srcs);
    k_sortw<<<((size_t)N*64+255)/256,256,0,stream>>>(indptr, srcs, N);

    int gRow = (N+63)/64;
    int gNode = (N+3)/4;

    // GAT1: 16 -> H x 32  (attn fused, HPT=2)
    k_gemm<16,32,0,1,2><<<dim3(gRow,320/64),256,0,stream>>>(nfA, WT1, nullptr, hf, N, 320, as1, ad1, es, ed);
    k_fused<32><<<gNode,256,0,stream>>>(indptr, srcs, es, ed, hf, bc1, nfB, N);

    // GAT2: 32 -> H x 64  (attn fused, HPT=1)
    k_gemm<32,32,0,1,1><<<dim3(gRow,640/64),256,0,stream>>>(nfB, WT2, nullptr, hf, N, 640, as2, ad2, es, ed);
    k_fused<64><<<gNode,256,0,stream>>>(indptr, srcs, es, ed, hf, bc2, nfA, N);

    // GAT3: 64 -> H x 128 (attn fused via 2-way atomic partials, HPT=-1)
    hipMemsetAsync(es, 0, (size_t)N*NHEADS*4, stream);
    hipMemsetAsync(ed, 0, (size_t)N*NHEADS*4, stream);
    k_gemm<64,64,0,1,-1><<<dim3(gRow,1280/64),256,0,stream>>>(nfA, WT3, nullptr, hf, N, 1280, as3, ad3, es, ed);
    k_fused<128><<<gNode,256,0,stream>>>(indptr, srcs, es, ed, hf, bc3, nfB, N);

    // fc1: [N,128]@[128,256] + bias + ELU (f32 out)
    k_gemm<128,128,1,0,0><<<dim3(gRow,256/64),256,0,stream>>>(nfB, WT4, b1, nfA, N, 256, nullptr, nullptr, nullptr, nullptr);
    // head
    k_head<<<(N+7)/8,256,0,stream>>>(nfA, W2, b2, out, N);
}

// Round 19
// 273.548 us; speedup vs baseline: 1.6532x; 1.0160x over previous
//
#include <hip/hip_runtime.h>
#include <hip/hip_bf16.h>
#include <math.h>

#define NHEADS 10

typedef unsigned short ushort_t;
typedef unsigned int uint_t;

typedef __attribute__((ext_vector_type(4))) float f32x4;
typedef __attribute__((ext_vector_type(8))) short short8;

__device__ __forceinline__ float bu2f(ushort_t u){ return __uint_as_float(((uint_t)u)<<16); }
__device__ __forceinline__ ushort_t f2bu(float f){
    uint_t b = __float_as_uint(f);
    return (ushort_t)((b + 0x7FFFu + ((b>>16)&1u)) >> 16);   // RNE
}

// ---------------- CSR scan ----------------
__global__ void k_scan(int* cnt, int N, int ET, int* indptr){
    __shared__ int lds[1024];
    int t = threadIdx.x;
    int chunk = (N + 1023)/1024;
    int base = t*chunk;
    int s = 0;
    for(int i=0;i<chunk;i++){ int idx=base+i; if(idx<N) s += cnt[idx]; }
    lds[t]=s;
    __syncthreads();
    for(int off=1; off<1024; off<<=1){
        int v = (t>=off)? lds[t-off] : 0;
        __syncthreads();
        lds[t]+=v;
        __syncthreads();
    }
    int run = lds[t]-s;
    for(int i=0;i<chunk;i++){
        int idx=base+i;
        if(idx<N){
            int c = cnt[idx];
            indptr[idx]=run;
            cnt[idx]=run;
            run += c;
        }
    }
    if(t==0) indptr[N]=ET;
}

__global__ void k_fill(const int* eidx, int E, int N, int* cursor, int* srcs){
    int e = blockIdx.x*blockDim.x + threadIdx.x;
    int ET = E + N;
    if(e >= ET) return;
    int s, d;
    if(e < E){ s = eidx[e]; d = eidx[E+e]; } else { s = e-E; d = e-E; }
    int pos = atomicAdd(&cursor[d], 1);
    srcs[pos] = s;
}

// wave-parallel bitonic sort of each node's src segment (1 wave / node)
__global__ void k_sortw(const int* indptr, int* srcs, int N){
    int wid  = (blockIdx.x*blockDim.x + threadIdx.x) >> 6;
    int lane = threadIdx.x & 63;
    if(wid >= N) return;
    int p0 = indptr[wid], p1 = indptr[wid+1];
    int deg = p1 - p0;
    if(deg <= 1) return;
    if(deg <= 64){
        int v = (lane < deg) ? srcs[p0+lane] : 0x7FFFFFFF;
        #pragma unroll
        for(int k=2; k<=64; k<<=1){
            #pragma unroll
            for(int j=k>>1; j>0; j>>=1){
                int partner = __shfl_xor(v, j, 64);
                bool dir   = ((lane & k) == 0);
                bool small = ((lane & j) == 0);
                int mn = min(v, partner), mx = max(v, partner);
                v = (dir == small) ? mn : mx;
            }
        }
        if(lane < deg) srcs[p0+lane] = v;
    } else if(lane == 0){               // safety fallback, statistically never
        for(int i=p0+1;i<p1;i++){
            int v2 = srcs[i]; int j=i-1;
            while(j>=p0 && srcs[j]>v2){ srcs[j+1]=srcs[j]; j--; }
            srcs[j+1]=v2;
        }
    }
}

// ---------------- setup: weight transposes + fc0 + CSR count + es3/ed3 zero ----------------
__global__ void k_setup(const float* __restrict__ W1c,const float* __restrict__ W2c,
                        const float* __restrict__ W3c,const float* __restrict__ W4c,
                        ushort_t* T1,ushort_t* T2,ushort_t* T3,ushort_t* T4,
                        const float* __restrict__ x, const float* __restrict__ W0,
                        const float* __restrict__ b0, float* __restrict__ fc0o,
                        const int* __restrict__ eidx, int* cnt,
                        float* es3, float* ed3, int E, int N){
    int idx = blockIdx.x*blockDim.x + threadIdx.x;
    if(idx < 10240){ int c=idx/32, k=idx%32; T1[idx] = (k<16)? f2bu(W1c[(size_t)k*320+c]) : (ushort_t)0; return; }
    idx -= 10240;
    if(idx < 20480){ int c=idx/32, k=idx%32; T2[idx] = f2bu(W2c[(size_t)k*640+c]); return; }
    idx -= 20480;
    if(idx < 81920){ int c=idx/64, k=idx%64; T3[idx] = f2bu(W3c[(size_t)k*1280+c]); return; }
    idx -= 81920;
    if(idx < 32768){ int c=idx/128, k=idx%128; T4[idx] = f2bu(W4c[(size_t)k*256+c]); return; }
    idx -= 32768;
    if(idx < N*16){
        int n = idx>>4, c = idx&15;
        float acc = b0[c];
        #pragma unroll
        for(int k=0;k<24;k++) acc += x[n*24+k] * W0[k*16+c];
        fc0o[idx] = acc>0.f ? acc : expm1f(acc);
        return;
    }
    idx -= N*16;
    if(idx < E+N){
        int d = (idx < E) ? eidx[E + idx] : (idx - E);
        atomicAdd(&cnt[d], 1);
        return;
    }
    idx -= E+N;
    if(idx < N*NHEADS){ es3[idx] = 0.f; ed3[idx] = 0.f; }
}

// ---------------- LDS-free MFMA GEMM (verified R11/R12), optional fused attention logits ----------------
// HPT: 2 = two heads per 64-col tile (C=32), 1 = one head (C=64),
//      -1 = half-head per tile with 2-way atomicAdd partials (C=128), 0 = none.
template<int K, int KP, int EPI, int OUTBF16, int HPT>
__global__ void __launch_bounds__(256, 4)
k_gemm(const float* __restrict__ A, const ushort_t* __restrict__ BT,
       const float* __restrict__ bias, void* __restrict__ Cmat,
       int N, int HC,
       const float* __restrict__ a_s, const float* __restrict__ a_d,
       float* __restrict__ es, float* __restrict__ ed){
    int t = threadIdx.x;
    int w = t >> 6, lane = t & 63;
    int lr = lane & 15, lk = lane >> 4;
    int row0 = blockIdx.x*64, col0 = blockIdx.y*64;
    int row = row0 + w*16 + lr;

    f32x4 acc[4];
    #pragma unroll
    for(int f=0; f<4; f++) acc[f] = (f32x4){0.f,0.f,0.f,0.f};

    #pragma unroll
    for(int kb = 0; kb < K; kb += 32){
        int k0 = kb + lk*8;
        short8 af = {0,0,0,0,0,0,0,0};
        if(row < N && k0 < K){
            const float* ap = &A[(size_t)row*K + k0];
            float4 a0 = *(const float4*)ap;
            float4 a1 = *(const float4*)(ap + 4);
            af[0]=(short)f2bu(a0.x); af[1]=(short)f2bu(a0.y);
            af[2]=(short)f2bu(a0.z); af[3]=(short)f2bu(a0.w);
            af[4]=(short)f2bu(a1.x); af[5]=(short)f2bu(a1.y);
            af[6]=(short)f2bu(a1.z); af[7]=(short)f2bu(a1.w);
        }
        #pragma unroll
        for(int f=0; f<4; f++){
            int col = col0 + f*16 + lr;
            short8 bf = *(const short8*)&BT[(size_t)col*KP + k0];
            acc[f] = __builtin_amdgcn_mfma_f32_16x16x32_bf16(af, bf, acc[f], 0, 0, 0);
        }
    }

    #pragma unroll
    for(int f=0; f<4; f++){
        #pragma unroll
        for(int j=0; j<4; j++){
            int r = row0 + w*16 + lk*4 + j;
            if(r >= N) continue;
            int col = col0 + f*16 + lr;
            float v = acc[f][j];
            if(EPI){
                v += bias[col];
                v = v>0.f ? v : expm1f(v);
            }
            if(OUTBF16) ((ushort_t*)Cmat)[(size_t)r*HC + col] = f2bu(v);
            else        ((float*)Cmat)[(size_t)r*HC + col] = v;
        }
    }

    if constexpr (HPT > 0){
        constexpr int CH = 64/HPT;
        #pragma unroll
        for(int j=0; j<4; j++){
            int r = row0 + w*16 + lk*4 + j;
            float sp[HPT], dp[HPT];
            #pragma unroll
            for(int g=0; g<HPT; g++){ sp[g]=0.f; dp[g]=0.f; }
            #pragma unroll
            for(int f=0; f<4; f++){
                float vb = bu2f(f2bu(acc[f][j]));
                int g   = (HPT==2) ? (f>>1) : 0;
                int cih = (HPT==2) ? ((f&1)*16 + lr) : (f*16 + lr);
                int ai  = col0 + g*CH + cih;
                sp[g] += vb * a_s[ai];
                dp[g] += vb * a_d[ai];
            }
            #pragma unroll
            for(int st=1; st<16; st<<=1){
                #pragma unroll
                for(int g=0; g<HPT; g++){
                    sp[g] += __shfl_xor(sp[g], st, 64);
                    dp[g] += __shfl_xor(dp[g], st, 64);
                }
            }
            if(lr == 0 && r < N){
                #pragma unroll
                for(int g=0; g<HPT; g++){
                    int head = col0/CH + g;
                    es[r*NHEADS + head] = sp[g];
                    ed[r*NHEADS + head] = dp[g];
                }
            }
        }
    }
    if constexpr (HPT == -1){
        // C=128: 64-col tile = half a head. Two commutative atomicAdds per (n,h) -> deterministic.
        int head = col0 >> 7;
        #pragma unroll
        for(int j=0; j<4; j++){
            int r = row0 + w*16 + lk*4 + j;
            float sp=0.f, dp=0.f;
            #pragma unroll
            for(int f=0; f<4; f++){
                float vb = bu2f(f2bu(acc[f][j]));
                int ai = (head<<7) + (col0 & 127) + f*16 + lr;
                sp += vb * a_s[ai];
                dp += vb * a_d[ai];
            }
            #pragma unroll
            for(int st=1; st<16; st<<=1){
                sp += __shfl_xor(sp, st, 64);
                dp += __shfl_xor(dp, st, 64);
            }
            if(lr == 0 && r < N){
                atomicAdd(&es[r*NHEADS + head], sp);
                atomicAdd(&ed[r*NHEADS + head], dp);
            }
        }
    }
}

// ---------------- fused softmax + aggregation (R18 structure, no launch_bounds) ----------------
// Occupancy experiment: VGPR=64 + LDS 10.75KB naturally permit 8 blocks/CU; the (256,4)
// bound capped residency at 4. R15 showed forcing (256,8) makes the allocator spill; here
// we remove the bound entirely and let the scheduler pack.
template<int C>
__global__ void
k_fused(const int* __restrict__ indptr, const int* __restrict__ srcs,
        const float* __restrict__ es, const float* __restrict__ ed,
        const ushort_t* __restrict__ hf, const float* __restrict__ bc,
        float* __restrict__ out, int N)
{
    __shared__ float wlds[4][64*NHEADS];
    __shared__ float stat[4][NHEADS];
    __shared__ int   degs[4];
    int wslot = threadIdx.x >> 6;
    int lane  = threadIdx.x & 63;
    int n = (blockIdx.x << 2) + wslot;
    bool valid = (n < N);
    int p0 = 0, deg = 0;
    if(valid){ p0 = indptr[n]; deg = indptr[n+1] - p0; }
    if(lane == 0) degs[wslot] = deg;
    __syncthreads();
    int maxdeg = max(max(degs[0],degs[1]), max(degs[2],degs[3]));
    int nch = (maxdeg + 63) >> 6;
    float* wl = wlds[wslot];

    int e6 = lane/10, h6 = lane%10;
    float edv = (valid && lane < 60) ? ed[n*NHEADS + h6] : 0.f;

    // ---- pass A: w = exp(leaky(e)) into LDS; den accumulated during fill, folded via shfl ----
    float denp = 0.f;
    for(int c = 0; c < nch; c++){
        int base = c << 6;
        int lim = deg - base; if(lim > 64) lim = 64; if(lim < 0) lim = 0;
        if(valid && lane < 60){
            for(int i = e6; i < lim; i += 6){
                float v = es[(size_t)srcs[p0+base+i]*NHEADS + h6] + edv;
                v = (v >= 0.f) ? v : 0.2f*v;
                float wv = expf(fminf(v, 60.f));
                wl[i*NHEADS + h6] = wv;
                denp += wv;
            }
        }
        __syncthreads();
    }
    float tA = __shfl(denp, lane+30, 64);
    if(lane < 30) denp += tA;
    float tB = __shfl(denp, lane+10, 64);
    float tC = __shfl(denp, lane+20, 64);
    if(lane < 10) denp += tB + tC;
    if(valid && lane < NHEADS) stat[wslot][lane] = 1.f/(denp + 1e-30f);
    __syncthreads();
    // normalize weights in LDS (nch==1 fast path)
    if(nch == 1 && valid && lane < 60){
        float dv = stat[wslot][h6];
        for(int i = e6; i < deg; i += 6) wl[i*NHEADS + h6] *= dv;
    }
    __syncthreads();

    constexpr int TPN = C/8;
    constexpr int EG  = 64/TPN;
    int local = lane % TPN, eg = lane / TPN;
    int c8 = local*8;
    float acc[8];
    #pragma unroll
    for(int i=0;i<8;i++) acc[i]=0.f;

    if(nch == 1){
        for(int i = eg; i < deg; i += EG){
            int s = srcs[p0+i];
            const ushort_t* hp = hf + (size_t)s*NHEADS*C + c8;
            const float2* wp2 = (const float2*)&wl[i*NHEADS];
            #pragma unroll
            for(int hh=0; hh<5; hh++){
                float2 wv = wp2[hh];
                uint4 q0 = *(const uint4*)(hp + (2*hh)*C);
                uint4 q1 = *(const uint4*)(hp + (2*hh+1)*C);
                float w0 = wv.x, w1 = wv.y;
                acc[0] += w0 * __uint_as_float(q0.x<<16) + w1 * __uint_as_float(q1.x<<16);
                acc[1] += w0 * __uint_as_float(q0.x & 0xFFFF0000u) + w1 * __uint_as_float(q1.x & 0xFFFF0000u);
                acc[2] += w0 * __uint_as_float(q0.y<<16) + w1 * __uint_as_float(q1.y<<16);
                acc[3] += w0 * __uint_as_float(q0.y & 0xFFFF0000u) + w1 * __uint_as_float(q1.y & 0xFFFF0000u);
                acc[4] += w0 * __uint_as_float(q0.z<<16) + w1 * __uint_as_float(q1.z<<16);
                acc[5] += w0 * __uint_as_float(q0.z & 0xFFFF0000u) + w1 * __uint_as_float(q1.z & 0xFFFF0000u);
                acc[6] += w0 * __uint_as_float(q0.w<<16) + w1 * __uint_as_float(q1.w<<16);
                acc[7] += w0 * __uint_as_float(q0.w & 0xFFFF0000u) + w1 * __uint_as_float(q1.w & 0xFFFF0000u);
            }
        }
    } else {
        // fallback chunked path (deg > 64; statistically never)
        float dinv_r[NHEADS];
        #pragma unroll
        for(int h=0; h<NHEADS; h++) dinv_r[h] = stat[wslot][h];
        for(int c = 0; c < nch; c++){
            int base = c << 6;
            int lim = deg - base; if(lim > 64) lim = 64; if(lim < 0) lim = 0;
            if(valid && lane < 60){
                for(int i = e6; i < lim; i += 6){
                    float v = es[(size_t)srcs[p0+base+i]*NHEADS + h6] + edv;
                    v = (v >= 0.f) ? v : 0.2f*v;
                    wl[i*NHEADS + h6] = expf(fminf(v, 60.f));
                }
            }
            __syncthreads();
            if(valid){
                for(int i = eg; i < lim; i += EG){
                    int s = srcs[p0+base+i];
                    const ushort_t* hp = hf + (size_t)s*NHEADS*C + c8;
                    const float* wp = &wl[i*NHEADS];
                    #pragma unroll
                    for(int h=0;h<NHEADS;h++){
                        uint4 q = *(const uint4*)(hp + h*C);
                        float wd = wp[h]*dinv_r[h];
                        acc[0] += wd * __uint_as_float(q.x<<16);
                        acc[1] += wd * __uint_as_float(q.x & 0xFFFF0000u);
                        acc[2] += wd * __uint_as_float(q.y<<16);
                        acc[3] += wd * __uint_as_float(q.y & 0xFFFF0000u);
                        acc[4] += wd * __uint_as_float(q.z<<16);
                        acc[5] += wd * __uint_as_float(q.z & 0xFFFF0000u);
                        acc[6] += wd * __uint_as_float(q.w<<16);
                        acc[7] += wd * __uint_as_float(q.w & 0xFFFF0000u);
                    }
                }
            }
            __syncthreads();
        }
    }

    #pragma unroll
    for(int s = TPN; s < 64; s <<= 1){
        #pragma unroll
        for(int i=0;i<8;i++) acc[i] += __shfl_xor(acc[i], s, 64);
    }
    if(valid && eg == 0){
        float4 v0, v1;
        #pragma unroll
        for(int i=0;i<8;i++){
            float v = acc[i]*(1.f/NHEADS) + bc[c8+i];
            v = v>0.f ? v : expm1f(v);
            if(i<4) ((float*)&v0)[i] = v; else ((float*)&v1)[i-4] = v;
        }
        *(float4*)&out[(size_t)n*C + c8]     = v0;
        *(float4*)&out[(size_t)n*C + c8 + 4] = v1;
    }
}

// ---------------- head: logits 256->24 + log_softmax ----------------
__global__ void k_head(const float* hin, const float* W2, const float* b2v, float* out, int N){
    int grp  = threadIdx.x/32;
    int lane = threadIdx.x%32;
    int n = blockIdx.x*8 + grp;
    if(n>=N) return;
    float acc = -1e30f;
    if(lane < 24){
        acc = b2v[lane];
        for(int k=0;k<256;k++) acc += hin[n*256+k]*W2[k*24+lane];
    }
    float mx = acc;
    for(int off=16; off; off>>=1) mx = fmaxf(mx, __shfl_xor(mx, off, 32));
    float ex = (lane<24)? expf(acc-mx) : 0.f;
    float sm = ex;
    for(int off=16; off; off>>=1) sm += __shfl_xor(sm, off, 32);
    if(lane<24) out[n*24+lane] = acc - mx - logf(sm);
}

extern "C" void kernel_launch(void* const* d_in, const int* in_sizes, int n_in,
                              void* d_out, int out_size, void* d_ws, size_t ws_size,
                              hipStream_t stream) {
    const float* x   = (const float*)d_in[0];
    const int*  eidx = (const int*)d_in[1];
    const float* W0 = (const float*)d_in[3];  const float* b0 = (const float*)d_in[4];
    const float* Wc1= (const float*)d_in[5];  const float* as1= (const float*)d_in[6];
    const float* ad1= (const float*)d_in[7];  const float* bc1= (const float*)d_in[8];
    const float* Wc2= (const float*)d_in[9];  const float* as2= (const float*)d_in[10];
    const float* ad2= (const float*)d_in[11]; const float* bc2= (const float*)d_in[12];
    const float* Wc3= (const float*)d_in[13]; const float* as3= (const float*)d_in[14];
    const float* ad3= (const float*)d_in[15]; const float* bc3= (const float*)d_in[16];
    const float* W1 = (const float*)d_in[17]; const float* b1 = (const float*)d_in[18];
    const float* W2 = (const float*)d_in[19]; const float* b2 = (const float*)d_in[20];
    float* out = (float*)d_out;

    const int N  = in_sizes[0]/24;
    const int E  = in_sizes[1]/2;
    const int ET = E + N;

    char* w = (char*)d_ws;
    size_t off = 0;
    auto alloc = [&](size_t bytes)->void* {
        void* p = w + off;
        off = (off + bytes + 255) & ~(size_t)255;
        return p;
    };
    int*   cnt    = (int*)  alloc((size_t)N*4);
    int*   indptr = (int*)  alloc((size_t)(N+1)*4);
    int*   srcs   = (int*)  alloc((size_t)ET*4);
    float* es     = (float*)alloc((size_t)N*NHEADS*4);
    float* ed     = (float*)alloc((size_t)N*NHEADS*4);
    float* es3    = (float*)alloc((size_t)N*NHEADS*4);
    float* ed3    = (float*)alloc((size_t)N*NHEADS*4);
    float* nfA    = (float*)alloc((size_t)N*256*4);
    float* nfB    = (float*)alloc((size_t)N*256*4);
    ushort_t* hf  = (ushort_t*)alloc((size_t)N*1280*2);
    ushort_t* WT1 = (ushort_t*)alloc((size_t)320*32*2);
    ushort_t* WT2 = (ushort_t*)alloc((size_t)640*32*2);
    ushort_t* WT3 = (ushort_t*)alloc((size_t)1280*64*2);
    ushort_t* WT4 = (ushort_t*)alloc((size_t)256*128*2);

    // setup: memset + (transposes | fc0 | CSR count | es3/ed3 zero) in one dispatch
    hipMemsetAsync(cnt, 0, (size_t)N*4, stream);
    int setupWork = 145408 + N*16 + ET + N*NHEADS;
    k_setup<<<(setupWork+255)/256,256,0,stream>>>(Wc1, Wc2, Wc3, W1, WT1, WT2, WT3, WT4,
                                                  x, W0, b0, nfA, eidx, cnt, es3, ed3, E, N);
    k_scan <<<1,1024,0,stream>>>(cnt, N, ET, indptr);
    int gE = (ET+255)/256;
    k_fill <<<gE,256,0,stream>>>(eidx, E, N, cnt, srcs);
    k_sortw<<<((size_t)N*64+255)/256,256,0,stream>>>(indptr, srcs, N);

    int gRow = (N+63)/64;
    int gNode = (N+3)/4;

    // GAT1: 16 -> H x 32  (attn fused, HPT=2)
    k_gemm<16,32,0,1,2><<<dim3(gRow,320/64),256,0,stream>>>(nfA, WT1, nullptr, hf, N, 320, as1, ad1, es, ed);
    k_fused<32><<<gNode,256,0,stream>>>(indptr, srcs, es, ed, hf, bc1, nfB, N);

    // GAT2: 32 -> H x 64  (attn fused, HPT=1)
    k_gemm<32,32,0,1,1><<<dim3(gRow,640/64),256,0,stream>>>(nfB, WT2, nullptr, hf, N, 640, as2, ad2, es, ed);
    k_fused<64><<<gNode,256,0,stream>>>(indptr, srcs, es, ed, hf, bc2, nfA, N);

    // GAT3: 64 -> H x 128 (attn fused via 2-way atomic partials into pre-zeroed es3/ed3)
    k_gemm<64,64,0,1,-1><<<dim3(gRow,1280/64),256,0,stream>>>(nfA, WT3, nullptr, hf, N, 1280, as3, ad3, es3, ed3);
    k_fused<128><<<gNode,256,0,stream>>>(indptr, srcs, es3, ed3, hf, bc3, nfB, N);

    // fc1: [N,128]@[128,256] + bias + ELU (f32 out)
    k_gemm<128,128,1,0,0><<<dim3(gRow,256/64),256,0,stream>>>(nfB, WT4, b1, nfA, N, 256, nullptr, nullptr, nullptr, nullptr);
    // head
    k_head<<<(N+7)/8,256,0,stream>>>(nfA, W2, b2, out, N);
}